// Round 7
// baseline (456.236 us; speedup 1.0000x reference)
//
#include <hip/hip_runtime.h>
#include <hip/hip_bf16.h>

#define N_NODES 100000
#define N_HEDGES 100000
#define N_INC 1600000
#define D 128

#define B_KEYS 512            // keys per bucket
#define NBUCK 196             // ceil(100000/512)
#define CAP 10240             // bucket capacity (mean 8192, sigma ~90)
#define CHUNK 4096            // 16 items per thread, register-resident
#define NBLKA ((N_INC + CHUNK - 1) / CHUNK)   // 391

#define LDA 136               // padded bf16 row stride for GEMM LDS tiles

// ---- feature-sliced planar layout: 8 planes of 16 features (32 B) ----
// plane s is contiguous 3.2 MB -> L2-resident on XCD s (blockIdx & 7).
// FETCH floor = col stream (~48-51 MB). Proven: sc0 buffer loads bypass L1
// (no 128-B line-fill amplification). Round-6 de-risk: fused 8-load + vmcnt(0)
// asm (round-5-proven pattern, no cross-block register ties), 4 lanes/segment
// (2 batches/wave instead of 7), OOB voffset masking (HW kills the request,
// returns 0 -> uniform control flow, no wasted transactions).
#define NSLICE 8
#define PLANE_SHORTS ((size_t)N_NODES * 16)
#define PLANE_BYTES  ((size_t)N_NODES * 32)
#define GBLK 1563             // ceil(100000 / 64) segment groups (64 segs/block)
#define LDSCOL 2048           // staged index capacity (mean 1024, +32 sigma)

typedef __attribute__((ext_vector_type(8))) short bf16x8;
typedef __attribute__((ext_vector_type(4))) float f32x4;
typedef __attribute__((ext_vector_type(4))) unsigned uint4v;

__device__ __forceinline__ short f2bf(float v) {
    __hip_bfloat16 b = __float2bfloat16(v);
    return *(short*)&b;
}
__device__ __forceinline__ unsigned packbf2(float x, float y) {
    __hip_bfloat162 p = __float22bfloat162_rn(make_float2(x, y));
    return *(unsigned*)&p;
}

// ---------------- W transpose + bf16 convert (once per call) ----------------
__global__ void wt_kernel(const float* __restrict__ W1, const float* __restrict__ W2,
                          short* __restrict__ WT1, short* __restrict__ WT2,
                          int* __restrict__ gcnt) {
    if (blockIdx.x == 0) {
        for (int i = threadIdx.x; i < 2 * NBUCK; i += 256) gcnt[i] = 0;
    }
    int idx = blockIdx.x * 256 + threadIdx.x;     // 0..32767
    int sel = idx >> 14;
    int li = idx & 16383;
    int n = li >> 7, k = li & 127;
    const float* src = sel ? W2 : W1;
    short* dst = sel ? WT2 : WT1;
    dst[li] = f2bf(src[k * 128 + n]);
}

// ---------------- Phase A: bucket partition, register-resident chunk ----------------
__launch_bounds__(256)
__global__ void binA_kernel(const int* __restrict__ nidx, const int* __restrict__ hidx,
                            int* __restrict__ gcnt_e, int* __restrict__ gcnt_n,
                            unsigned* __restrict__ bin_e, unsigned* __restrict__ bin_n) {
    __shared__ int hist_e[NBUCK], hist_n[NBUCK], base_e[NBUCK], base_n[NBUCK];
    int t = threadIdx.x;
    int items_h[16], items_n[16];
    int start = blockIdx.x * CHUNK;
#pragma unroll
    for (int k = 0; k < 16; ++k) {
        int i = start + t + k * 256;
        bool ok = i < N_INC;
        items_h[k] = ok ? hidx[i] : -1;
        items_n[k] = ok ? nidx[i] : -1;
    }
    for (int b = t; b < NBUCK; b += 256) { hist_e[b] = 0; hist_n[b] = 0; }
    __syncthreads();
#pragma unroll
    for (int k = 0; k < 16; ++k) {
        if (items_h[k] >= 0) {
            atomicAdd(&hist_e[items_h[k] >> 9], 1);
            atomicAdd(&hist_n[items_n[k] >> 9], 1);
        }
    }
    __syncthreads();
    for (int b = t; b < NBUCK; b += 256) {
        base_e[b] = atomicAdd(&gcnt_e[b], hist_e[b]);
        base_n[b] = atomicAdd(&gcnt_n[b], hist_n[b]);
        hist_e[b] = 0; hist_n[b] = 0;
    }
    __syncthreads();
#pragma unroll
    for (int k = 0; k < 16; ++k) {
        if (items_h[k] >= 0) {
            int h = items_h[k], n = items_n[k];
            int be = h >> 9, bn = n >> 9;
            int oe = base_e[be] + atomicAdd(&hist_e[be], 1);
            if (oe >= 0 && oe < CAP) bin_e[(size_t)be * CAP + oe] = ((unsigned)(h & 511) << 17) | (unsigned)n;
            int on = base_n[bn] + atomicAdd(&hist_n[bn], 1);
            if (on >= 0 && on < CAP) bin_n[(size_t)bn * CAP + on] = ((unsigned)(n & 511) << 17) | (unsigned)h;
        }
    }
}

// ---------------- Phase B: per-bucket counting sort, wave-shuffle scan ----------
__launch_bounds__(512)
__global__ void binB2_kernel(const int* __restrict__ gcnt_e, const unsigned* __restrict__ bin_e,
                             int* __restrict__ csr_e, int2* __restrict__ meta_e,
                             const int* __restrict__ gcnt_n, const unsigned* __restrict__ bin_n,
                             int* __restrict__ csr_n, int2* __restrict__ meta_n) {
    __shared__ int kc[B_KEYS];
    __shared__ int wsum[8];
    int b = blockIdx.x;
    const int* gcnt;  const unsigned* bin;  int* csr;  int2* meta;
    if (b < NBUCK) { gcnt = gcnt_e; bin = bin_e; csr = csr_e; meta = meta_e; }
    else { b -= NBUCK; gcnt = gcnt_n; bin = bin_n; csr = csr_n; meta = meta_n; }
    int t = threadIdx.x;
    int lane = t & 63, wv = t >> 6;
    int cnt = gcnt[b];
    if (cnt > CAP) cnt = CAP;
    kc[t] = 0;
    __syncthreads();
    const unsigned* items = bin + (size_t)b * CAP;
    for (int i = t; i < cnt; i += 512) atomicAdd(&kc[items[i] >> 17], 1);
    __syncthreads();
    int mycnt = kc[t];
    int v = mycnt;
#pragma unroll
    for (int off = 1; off < 64; off <<= 1) {
        int u = __shfl_up(v, off);
        if (lane >= off) v += u;
    }
    if (lane == 63) wsum[wv] = v;
    __syncthreads();
    int addp = 0;
#pragma unroll
    for (int w = 0; w < 7; ++w) addp += (w < wv) ? wsum[w] : 0;
    int incl = v + addp;
    int sstart = b * CAP + (incl - mycnt);   // exclusive start
    meta[b * B_KEYS + t] = make_int2(sstart, mycnt);
    kc[t] = sstart;
    __syncthreads();
    for (int i = t; i < cnt; i += 512) {
        unsigned it = items[i];
        int pos = atomicAdd(&kc[it >> 17], 1);
        csr[pos] = (int)(it & 0x1FFFFu);
    }
}

// ---------------- MFMA bf16 GEMM: planar output [8][N][16 feats] ----------------
template <bool PLANAR>
__launch_bounds__(256)
__global__ void gemm_mfma_kernel(const void* __restrict__ Xv, const short* __restrict__ WT,
                                 char* __restrict__ Y, int nrows) {
    __shared__ short lds_w[128 * LDA];   // W^T [n][k]; later reused for C staging
    int tid = threadIdx.x;
    int row0 = blockIdx.x * 64;

    {
        const uint4* w4 = (const uint4*)WT;
#pragma unroll
        for (int i = 0; i < 8; ++i) {
            int idx = tid + i * 256;          // 0..2047 = 128 rows x 16 uint4
            int n = idx >> 4, g = idx & 15;
            *(uint4*)(lds_w + n * LDA + g * 8) = w4[idx];
        }
    }

    int wv = tid >> 6, lane = tid & 63;
    int m = lane & 15, quad = lane >> 4;
    int row = row0 + wv * 16 + m;
    bool rowok = row < nrows;

    bf16x8 af[4];
    if constexpr (!PLANAR) {
        const float* xr = (const float*)Xv + (size_t)row * 128 + quad * 8;
#pragma unroll
        for (int k0 = 0; k0 < 4; ++k0) {
            float4 a0 = make_float4(0.f, 0.f, 0.f, 0.f), a1 = a0;
            if (rowok) {
                a0 = *(const float4*)(xr + k0 * 32);
                a1 = *(const float4*)(xr + k0 * 32 + 4);
            }
            bf16x8 f;
            f[0] = f2bf(a0.x); f[1] = f2bf(a0.y); f[2] = f2bf(a0.z); f[3] = f2bf(a0.w);
            f[4] = f2bf(a1.x); f[5] = f2bf(a1.y); f[6] = f2bf(a1.z); f[7] = f2bf(a1.w);
            af[k0] = f;
        }
    } else {
        const short* X = (const short*)Xv;
#pragma unroll
        for (int k0 = 0; k0 < 4; ++k0) {
            int p = k0 * 2 + (quad >> 1);
            bf16x8 f = {0, 0, 0, 0, 0, 0, 0, 0};
            if (rowok) f = *(const bf16x8*)(X + (size_t)p * PLANE_SHORTS + (size_t)row * 16 + (quad & 1) * 8);
            af[k0] = f;
        }
    }
    __syncthreads();   // W staged

    f32x4 zero = {0.f, 0.f, 0.f, 0.f};
    f32x4 acc[8];
#pragma unroll
    for (int t8 = 0; t8 < 8; ++t8) acc[t8] = zero;

#pragma unroll
    for (int t8 = 0; t8 < 8; ++t8) {
        const short* brow = lds_w + (t8 * 16 + m) * LDA + quad * 8;
#pragma unroll
        for (int k0 = 0; k0 < 4; ++k0) {
            bf16x8 bf = *(const bf16x8*)(brow + k0 * 32);
            acc[t8] = __builtin_amdgcn_mfma_f32_16x16x32_bf16(af[k0], bf, acc[t8], 0, 0, 0);
        }
    }

    __syncthreads();   // all W ds_reads done; reuse lds_w for C staging
    // C/D layout: col = lane&15, row = quad*4 + reg
#pragma unroll
    for (int t8 = 0; t8 < 8; ++t8) {
#pragma unroll
        for (int r = 0; r < 4; ++r) {
            int crow = wv * 16 + quad * 4 + r;
            int col = t8 * 16 + m;
            lds_w[crow * LDA + col] = f2bf(acc[t8][r]);
        }
    }
    __syncthreads();
    // planar store: per wave one plane, 64 rows x 2 halves = 1 KB contiguous
#pragma unroll
    for (int i = 0; i < 4; ++i) {
        int idx = tid + i * 256;              // 0..1023
        int slice = idx >> 7, j = idx & 127;  // j = row*2 + half
        int r = j >> 1, h = j & 1;
        if (row0 + r < nrows) {
            uint4 u = *(const uint4*)(lds_w + r * LDA + slice * 16 + h * 8);
            *(uint4*)(Y + (size_t)slice * PLANE_BYTES + (size_t)(row0 + r) * 32 + h * 16) = u;
        }
    }
}

// ---------------- sc0 (L1-bypass) fused gather: 8 loads in flight ----------------
__device__ __forceinline__ uint4v srsrc_make(const void* base, unsigned bytes) {
    union { struct { unsigned lo, hi, nrec, flags; } s; uint4v v; } u;
    unsigned long long p = (unsigned long long)base;
    u.s.lo = (unsigned)p;
    u.s.hi = (unsigned)(p >> 32);      // stride = 0
    u.s.nrec = bytes;                  // num_records in bytes
    u.s.flags = 0x00020000u;           // raw dword access
    return u.v;
}
// all 8 loads issue back-to-back (8 outstanding), then one wait. Outputs are
// architecturally complete when the asm ends (round-5-proven pattern).
__device__ __forceinline__ void gather8_sc0(uint4v rsrc,
        unsigned o0, unsigned o1, unsigned o2, unsigned o3,
        unsigned o4, unsigned o5, unsigned o6, unsigned o7,
        uint4v& u0, uint4v& u1, uint4v& u2, uint4v& u3,
        uint4v& u4, uint4v& u5, uint4v& u6, uint4v& u7) {
    asm volatile("buffer_load_dwordx4 %0, %8, %16, 0 offen sc0\n\t"
                 "buffer_load_dwordx4 %1, %9, %16, 0 offen sc0\n\t"
                 "buffer_load_dwordx4 %2, %10, %16, 0 offen sc0\n\t"
                 "buffer_load_dwordx4 %3, %11, %16, 0 offen sc0\n\t"
                 "buffer_load_dwordx4 %4, %12, %16, 0 offen sc0\n\t"
                 "buffer_load_dwordx4 %5, %13, %16, 0 offen sc0\n\t"
                 "buffer_load_dwordx4 %6, %14, %16, 0 offen sc0\n\t"
                 "buffer_load_dwordx4 %7, %15, %16, 0 offen sc0\n\t"
                 "s_waitcnt vmcnt(0)"
                 : "=&v"(u0), "=&v"(u1), "=&v"(u2), "=&v"(u3),
                   "=&v"(u4), "=&v"(u5), "=&v"(u6), "=&v"(u7)
                 : "v"(o0), "v"(o1), "v"(o2), "v"(o3),
                   "v"(o4), "v"(o5), "v"(o6), "v"(o7), "s"(rsrc));
}

__device__ __forceinline__ void acc8_add(float* a, uint4v u) {
    a[0] += __uint_as_float(u[0] << 16); a[1] += __uint_as_float(u[0] & 0xFFFF0000u);
    a[2] += __uint_as_float(u[1] << 16); a[3] += __uint_as_float(u[1] & 0xFFFF0000u);
    a[4] += __uint_as_float(u[2] << 16); a[5] += __uint_as_float(u[2] & 0xFFFF0000u);
    a[6] += __uint_as_float(u[3] << 16); a[7] += __uint_as_float(u[3] & 0xFFFF0000u);
}

// MODE 0: edge agg (scale only, planar bf16 out)
// MODE 1: node agg + bias + relu (planar bf16 out)
// MODE 2: node agg + bias + relu -> per-block 16-col partials (dst = float*)
//
// Structure: 4 lanes per segment (2 halves x 2 item-parity), 16 segs/wave,
// 64 segs/block. Indices LDS-staged coalesced. Uniform batch loop (wave-max
// trip count); masked lanes use OOB voffset -> HW bounds check kills the
// request and returns 0 (+0.0f add). ~2 batches of 8 in-flight loads per wave.
template <int MODE>
__launch_bounds__(256)
__global__ void agg_planar_kernel(const char* __restrict__ src, const int2* __restrict__ meta,
                                  const int* __restrict__ col, const float* __restrict__ bias,
                                  char* __restrict__ dst) {
    __shared__ int lds_col[LDSCOL];
    int slice = blockIdx.x & 7;
    int g = blockIdx.x >> 3;
    int tid = threadIdx.x;
    int lane = tid & 63, wid = tid >> 6;
    int half = tid & 1;               // 16-B half of the 32-B row
    int ip = (tid >> 1) & 1;          // item parity
    int seg = g * 64 + (tid >> 2);
    bool segok = seg < N_NODES;
    const char* plane = src + (size_t)slice * PLANE_BYTES;
    uint4v rsrc = srsrc_make(plane, (unsigned)PLANE_BYTES);

    // block-contiguous CSR range [r0, r0+total): 64 consecutive segs in one bucket
    int gbase = g * 64;
    int2 mF = meta[gbase];
    int2 mL = meta[gbase + 63];
    int r0 = mF.x;
    int total = mL.x + mL.y - r0;
    if (total > LDSCOL) total = LDSCOL;     // +32 sigma, never in practice

    for (int i = tid; i < total; i += 256) lds_col[i] = col[r0 + i];

    float b8[8];
    if constexpr (MODE >= 1) {
        const float4* b4 = (const float4*)(bias + slice * 16 + half * 8);
        float4 lo = b4[0], hi = b4[1];
        b8[0] = lo.x; b8[1] = lo.y; b8[2] = lo.z; b8[3] = lo.w;
        b8[4] = hi.x; b8[5] = hi.y; b8[6] = hi.z; b8[7] = hi.w;
    }

    int2 mt = meta[seg];
    int ls = mt.x - r0;
    int cnt = segok ? mt.y : 0;
    if (ls < 0 || ls + cnt > total) cnt = 0;   // consistency with the clamp
    __syncthreads();

    // wave-uniform batch count
    int nm = cnt;
#pragma unroll
    for (int o = 1; o < 64; o <<= 1) { int u = __shfl_xor(nm, o); nm = nm > u ? nm : u; }
    int K = (nm + 1) >> 1;            // items per lane (j = ip + 2k)
    int B = (K + 7) >> 3;             // 8-item batches

    float acc[8] = {0.f, 0.f, 0.f, 0.f, 0.f, 0.f, 0.f, 0.f};
    unsigned hoff = (unsigned)half * 16u;

    auto mkoff = [&](int k) -> unsigned {
        int j = ip + 2 * k;
        bool v = j < cnt;
        int a = v ? (ls + j) : 0;
        unsigned idx = (unsigned)lds_col[a];
        return v ? ((idx << 5) + hoff) : 0x7FFFFF00u;   // OOB -> request killed, returns 0
    };

    for (int b = 0; b < B; ++b) {
        int k = b << 3;
        unsigned o0 = mkoff(k),     o1 = mkoff(k + 1), o2 = mkoff(k + 2), o3 = mkoff(k + 3);
        unsigned o4 = mkoff(k + 4), o5 = mkoff(k + 5), o6 = mkoff(k + 6), o7 = mkoff(k + 7);
        uint4v u0, u1, u2, u3, u4, u5, u6, u7;
        gather8_sc0(rsrc, o0, o1, o2, o3, o4, o5, o6, o7,
                    u0, u1, u2, u3, u4, u5, u6, u7);
        acc8_add(acc, u0); acc8_add(acc, u1); acc8_add(acc, u2); acc8_add(acc, u3);
        acc8_add(acc, u4); acc8_add(acc, u5); acc8_add(acc, u6); acc8_add(acc, u7);
    }

    // merge item parities: lanes tid^2 hold the other parity of the same seg-half
#pragma unroll
    for (int i = 0; i < 8; ++i) acc[i] += __shfl_xor(acc[i], 2);

    float sc = cnt ? 1.0f / (float)cnt : 0.0f;
    if constexpr (MODE == 0) {
        if (segok && ip == 0) {
            uint4 o;
            o.x = packbf2(acc[0] * sc, acc[1] * sc);
            o.y = packbf2(acc[2] * sc, acc[3] * sc);
            o.z = packbf2(acc[4] * sc, acc[5] * sc);
            o.w = packbf2(acc[6] * sc, acc[7] * sc);
            *(uint4*)(dst + (size_t)slice * PLANE_BYTES + (size_t)seg * 32 + half * 16) = o;
        }
    } else if constexpr (MODE == 1) {
        if (segok && ip == 0) {
            uint4 o;
            o.x = packbf2(fmaxf(fmaf(acc[0], sc, b8[0]), 0.f), fmaxf(fmaf(acc[1], sc, b8[1]), 0.f));
            o.y = packbf2(fmaxf(fmaf(acc[2], sc, b8[2]), 0.f), fmaxf(fmaf(acc[3], sc, b8[3]), 0.f));
            o.z = packbf2(fmaxf(fmaf(acc[4], sc, b8[4]), 0.f), fmaxf(fmaf(acc[5], sc, b8[5]), 0.f));
            o.w = packbf2(fmaxf(fmaf(acc[6], sc, b8[6]), 0.f), fmaxf(fmaf(acc[7], sc, b8[7]), 0.f));
            *(uint4*)(dst + (size_t)slice * PLANE_BYTES + (size_t)seg * 32 + half * 16) = o;
        }
    } else {
        // relu(acc*sc + b); ip==0 lanes carry the value, reduce over 16 segs/wave
        float v8[8];
#pragma unroll
        for (int i = 0; i < 8; ++i)
            v8[i] = (segok && ip == 0) ? fmaxf(fmaf(acc[i], sc, b8[i]), 0.f) : 0.f;
#pragma unroll
        for (int i = 0; i < 8; ++i) {
            v8[i] += __shfl_xor(v8[i], 4);
            v8[i] += __shfl_xor(v8[i], 8);
            v8[i] += __shfl_xor(v8[i], 16);
            v8[i] += __shfl_xor(v8[i], 32);
        }
        __shared__ float sp[4][16];
        if (lane < 2) {
#pragma unroll
            for (int i = 0; i < 8; ++i) sp[wid][half * 8 + i] = v8[i];
        }
        __syncthreads();
        if (tid < 16) {
            float r = sp[0][tid] + sp[1][tid] + sp[2][tid] + sp[3][tid];
            ((float*)dst)[((size_t)slice * GBLK + g) * 16 + tid] = r;
        }
    }
}

// ---------------- mean: reduce per-block partials [8][GBLK][16] ----------------
__launch_bounds__(256)
__global__ void mean_kernel(const float* __restrict__ partials, float* __restrict__ out) {
    __shared__ float sd[256];
    int f = blockIdx.x;               // 0..127
    int slice = f >> 4, w = f & 15;
    float s = 0.f;
    for (int g = threadIdx.x; g < GBLK; g += 256)
        s += partials[((size_t)slice * GBLK + g) * 16 + w];
    sd[threadIdx.x] = s;
    __syncthreads();
#pragma unroll
    for (int o = 128; o > 0; o >>= 1) {
        if (threadIdx.x < o) sd[threadIdx.x] += sd[threadIdx.x + o];
        __syncthreads();
    }
    if (threadIdx.x == 0) out[f] = sd[0] * (1.0f / (float)N_NODES);
}

// ---------------- launch ----------------
extern "C" void kernel_launch(void* const* d_in, const int* in_sizes, int n_in,
                              void* d_out, int out_size, void* d_ws, size_t ws_size,
                              hipStream_t stream) {
    const float* x  = (const float*)d_in[0];
    const int*   ei = (const int*)d_in[1];
    const float* w1 = (const float*)d_in[2];
    const float* b1 = (const float*)d_in[3];
    const float* w2 = (const float*)d_in[4];
    const float* b2 = (const float*)d_in[5];
    float* out = (float*)d_out;
    const int* nidx = ei;
    const int* hidx = ei + N_INC;

    char* wsp = (char*)d_ws;
    size_t off = 0;
    auto alloc = [&](size_t bytes) -> void* {
        void* p = wsp + off;
        off += (bytes + 255) & ~(size_t)255;
        return p;
    };

    char* B0         = (char*)alloc((size_t)N_NODES * 128 * 2);   // planar bf16
    char* B1         = (char*)alloc((size_t)N_NODES * 128 * 2);   // planar bf16
    unsigned* bin_e  = (unsigned*)alloc((size_t)NBUCK * CAP * 4);
    unsigned* bin_n  = (unsigned*)alloc((size_t)NBUCK * CAP * 4);
    int* csr_e       = (int*)alloc((size_t)NBUCK * CAP * 4);
    int* csr_n       = (int*)alloc((size_t)NBUCK * CAP * 4);
    float* partials  = (float*)alloc((size_t)NSLICE * GBLK * 16 * 4);
    int2* meta_e     = (int2*)alloc((size_t)NBUCK * B_KEYS * 8);
    int2* meta_n     = (int2*)alloc((size_t)NBUCK * B_KEYS * 8);
    short* WT1       = (short*)alloc((size_t)128 * 128 * 2);
    short* WT2       = (short*)alloc((size_t)128 * 128 * 2);
    int* gcnt        = (int*)alloc((size_t)2 * NBUCK * 4);
    int* gcnt_e = gcnt;
    int* gcnt_n = gcnt + NBUCK;

    wt_kernel<<<128, 256, 0, stream>>>(w1, w2, WT1, WT2, gcnt);
    binA_kernel<<<NBLKA, 256, 0, stream>>>(nidx, hidx, gcnt_e, gcnt_n, bin_e, bin_n);
    binB2_kernel<<<2 * NBUCK, 512, 0, stream>>>(gcnt_e, bin_e, csr_e, meta_e,
                                                gcnt_n, bin_n, csr_n, meta_n);

    int gGemm = (N_NODES + 63) / 64;
    int gAgg = NSLICE * GBLK;

    // layer 1
    gemm_mfma_kernel<false><<<gGemm, 256, 0, stream>>>(x, WT1, B0, N_NODES);
    agg_planar_kernel<0><<<gAgg, 256, 0, stream>>>(B0, meta_e, csr_e, nullptr, B1);
    agg_planar_kernel<1><<<gAgg, 256, 0, stream>>>(B1, meta_n, csr_n, b1, B0);
    // layer 2
    gemm_mfma_kernel<true><<<gGemm, 256, 0, stream>>>(B0, WT2, B1, N_NODES);
    agg_planar_kernel<0><<<gAgg, 256, 0, stream>>>(B1, meta_e, csr_e, nullptr, B0);
    agg_planar_kernel<2><<<gAgg, 256, 0, stream>>>(B0, meta_n, csr_n, b2, (char*)partials);
    mean_kernel<<<128, 256, 0, stream>>>(partials, out);
}

// Round 8
// 303.771 us; speedup vs baseline: 1.5019x; 1.5019x over previous
//
#include <hip/hip_runtime.h>
#include <hip/hip_bf16.h>

#define N_NODES 100000
#define N_HEDGES 100000
#define N_INC 1600000
#define D 128

#define B_KEYS 512            // keys per bucket
#define NBUCK 196             // ceil(100000/512)
#define CAP 10240             // bucket capacity (mean 8192, sigma ~90)
#define CHUNK 4096            // 16 items per thread, register-resident
#define NBLKA ((N_INC + CHUNK - 1) / CHUNK)   // 391

#define LDA 136               // padded bf16 row stride for GEMM W tile
#define LDC 144               // padded fp8 byte row stride for GEMM C staging

// fp8 row-major gather layout: row = 128 features x 1 B = exactly one 128-B
// line; 8 consecutive lanes x 16 B coalesce to ONE transaction per row.
// Halves both transaction count (3.2M -> 1.6M per pass) and LLC->L2 fill
// (~181 -> ~90-130 MB) vs the bf16 baseline that sat at the request wall.
#define GAGG 3125             // 100000 / 32 segs per block (exact)
#define LDSCOL 1024           // staged index run per block (mean 512, +22 sigma)

typedef __attribute__((ext_vector_type(8))) short bf16x8;
typedef __attribute__((ext_vector_type(4))) float f32x4;
typedef __attribute__((ext_vector_type(2))) float f32x2;

#if __has_builtin(__builtin_amdgcn_cvt_pk_f32_fp8) && __has_builtin(__builtin_amdgcn_cvt_pk_fp8_f32)
#define FP8_HW 1
#else
#define FP8_HW 0
#endif

__device__ __forceinline__ short f2bf(float v) {
    __hip_bfloat16 b = __float2bfloat16(v);
    return *(short*)&b;
}
__device__ __forceinline__ unsigned packbf2(float x, float y) {
    __hip_bfloat162 p = __float22bfloat162_rn(make_float2(x, y));
    return *(unsigned*)&p;
}

// ---------------- fp8 e4m3 helpers (HW cvt with guarded SW fallback) --------
#if !FP8_HW
__device__ __forceinline__ float fp8dec(unsigned b) {
    unsigned em = b & 0x7Fu;
    float mag = (em >= 8u)
        ? __uint_as_float((((em >> 3) + 120u) << 23) | ((em & 7u) << 20))
        : (float)em * 0x1.0p-9f;                 // denormal: m * 2^-9
    return (b & 0x80u) ? -mag : mag;
}
#endif

__device__ __forceinline__ unsigned char f2fp8(float v) {
#if FP8_HW
    return (unsigned char)(__builtin_amdgcn_cvt_pk_fp8_f32(v, v, 0, false) & 0xFF);
#else
    unsigned s = (__float_as_uint(v) >> 24) & 0x80u;
    float a = fabsf(v);
    a = fminf(a, 448.0f);
    unsigned q;
    if (a < 0x1.0p-6f) {
        q = (unsigned)__float2int_rn(a * 512.0f);       // denormal, RNE
    } else {
        unsigned u = __float_as_uint(a * 0x1.0p-120f);  // exponent re-bias
        unsigned rest = u & 0xFFFFFu;
        q = u >> 20;
        q += (rest > 0x80000u) || (rest == 0x80000u && (q & 1u));  // RNE
    }
    if (q > 0x7Eu) q = 0x7Eu;                           // cap at 448, avoid NaN
    return (unsigned char)(s | q);
#endif
}

__device__ __forceinline__ unsigned pack4fp8(float a, float b, float c, float d) {
#if FP8_HW
    unsigned v = (unsigned)__builtin_amdgcn_cvt_pk_fp8_f32(a, b, 0, false);
    v = (unsigned)__builtin_amdgcn_cvt_pk_fp8_f32(c, d, (int)v, true);
    return v;
#else
    return (unsigned)f2fp8(a) | ((unsigned)f2fp8(b) << 8) |
           ((unsigned)f2fp8(c) << 16) | ((unsigned)f2fp8(d) << 24);
#endif
}

__device__ __forceinline__ void accum16(float* a, uint4 u) {
#if FP8_HW
    f32x2 p;
    p = __builtin_amdgcn_cvt_pk_f32_fp8((int)u.x, false); a[0]  += p.x; a[1]  += p.y;
    p = __builtin_amdgcn_cvt_pk_f32_fp8((int)u.x, true);  a[2]  += p.x; a[3]  += p.y;
    p = __builtin_amdgcn_cvt_pk_f32_fp8((int)u.y, false); a[4]  += p.x; a[5]  += p.y;
    p = __builtin_amdgcn_cvt_pk_f32_fp8((int)u.y, true);  a[6]  += p.x; a[7]  += p.y;
    p = __builtin_amdgcn_cvt_pk_f32_fp8((int)u.z, false); a[8]  += p.x; a[9]  += p.y;
    p = __builtin_amdgcn_cvt_pk_f32_fp8((int)u.z, true);  a[10] += p.x; a[11] += p.y;
    p = __builtin_amdgcn_cvt_pk_f32_fp8((int)u.w, false); a[12] += p.x; a[13] += p.y;
    p = __builtin_amdgcn_cvt_pk_f32_fp8((int)u.w, true);  a[14] += p.x; a[15] += p.y;
#else
    unsigned w[4] = {u.x, u.y, u.z, u.w};
#pragma unroll
    for (int d = 0; d < 4; ++d) {
        a[d*4+0] += fp8dec(w[d] & 0xFF);
        a[d*4+1] += fp8dec((w[d] >> 8) & 0xFF);
        a[d*4+2] += fp8dec((w[d] >> 16) & 0xFF);
        a[d*4+3] += fp8dec(w[d] >> 24);
    }
#endif
}

// ---------------- W transpose + bf16 convert (once per call) ----------------
__global__ void wt_kernel(const float* __restrict__ W1, const float* __restrict__ W2,
                          short* __restrict__ WT1, short* __restrict__ WT2,
                          int* __restrict__ gcnt) {
    if (blockIdx.x == 0) {
        for (int i = threadIdx.x; i < 2 * NBUCK; i += 256) gcnt[i] = 0;
    }
    int idx = blockIdx.x * 256 + threadIdx.x;     // 0..32767
    int sel = idx >> 14;
    int li = idx & 16383;
    int n = li >> 7, k = li & 127;
    const float* src = sel ? W2 : W1;
    short* dst = sel ? WT2 : WT1;
    dst[li] = f2bf(src[k * 128 + n]);
}

// ---------------- Phase A: bucket partition, register-resident chunk ----------------
__launch_bounds__(256)
__global__ void binA_kernel(const int* __restrict__ nidx, const int* __restrict__ hidx,
                            int* __restrict__ gcnt_e, int* __restrict__ gcnt_n,
                            unsigned* __restrict__ bin_e, unsigned* __restrict__ bin_n) {
    __shared__ int hist_e[NBUCK], hist_n[NBUCK], base_e[NBUCK], base_n[NBUCK];
    int t = threadIdx.x;
    int items_h[16], items_n[16];
    int start = blockIdx.x * CHUNK;
#pragma unroll
    for (int k = 0; k < 16; ++k) {
        int i = start + t + k * 256;
        bool ok = i < N_INC;
        items_h[k] = ok ? hidx[i] : -1;
        items_n[k] = ok ? nidx[i] : -1;
    }
    for (int b = t; b < NBUCK; b += 256) { hist_e[b] = 0; hist_n[b] = 0; }
    __syncthreads();
#pragma unroll
    for (int k = 0; k < 16; ++k) {
        if (items_h[k] >= 0) {
            atomicAdd(&hist_e[items_h[k] >> 9], 1);
            atomicAdd(&hist_n[items_n[k] >> 9], 1);
        }
    }
    __syncthreads();
    for (int b = t; b < NBUCK; b += 256) {
        base_e[b] = atomicAdd(&gcnt_e[b], hist_e[b]);
        base_n[b] = atomicAdd(&gcnt_n[b], hist_n[b]);
        hist_e[b] = 0; hist_n[b] = 0;
    }
    __syncthreads();
#pragma unroll
    for (int k = 0; k < 16; ++k) {
        if (items_h[k] >= 0) {
            int h = items_h[k], n = items_n[k];
            int be = h >> 9, bn = n >> 9;
            int oe = base_e[be] + atomicAdd(&hist_e[be], 1);
            if (oe >= 0 && oe < CAP) bin_e[(size_t)be * CAP + oe] = ((unsigned)(h & 511) << 17) | (unsigned)n;
            int on = base_n[bn] + atomicAdd(&hist_n[bn], 1);
            if (on >= 0 && on < CAP) bin_n[(size_t)bn * CAP + on] = ((unsigned)(n & 511) << 17) | (unsigned)h;
        }
    }
}

// ---------------- Phase B: per-bucket counting sort, wave-shuffle scan ----------
__launch_bounds__(512)
__global__ void binB2_kernel(const int* __restrict__ gcnt_e, const unsigned* __restrict__ bin_e,
                             int* __restrict__ csr_e, int2* __restrict__ meta_e,
                             const int* __restrict__ gcnt_n, const unsigned* __restrict__ bin_n,
                             int* __restrict__ csr_n, int2* __restrict__ meta_n) {
    __shared__ int kc[B_KEYS];
    __shared__ int wsum[8];
    int b = blockIdx.x;
    const int* gcnt;  const unsigned* bin;  int* csr;  int2* meta;
    if (b < NBUCK) { gcnt = gcnt_e; bin = bin_e; csr = csr_e; meta = meta_e; }
    else { b -= NBUCK; gcnt = gcnt_n; bin = bin_n; csr = csr_n; meta = meta_n; }
    int t = threadIdx.x;
    int lane = t & 63, wv = t >> 6;
    int cnt = gcnt[b];
    if (cnt > CAP) cnt = CAP;
    kc[t] = 0;
    __syncthreads();
    const unsigned* items = bin + (size_t)b * CAP;
    for (int i = t; i < cnt; i += 512) atomicAdd(&kc[items[i] >> 17], 1);
    __syncthreads();
    int mycnt = kc[t];
    int v = mycnt;
#pragma unroll
    for (int off = 1; off < 64; off <<= 1) {
        int u = __shfl_up(v, off);
        if (lane >= off) v += u;
    }
    if (lane == 63) wsum[wv] = v;
    __syncthreads();
    int addp = 0;
#pragma unroll
    for (int w = 0; w < 7; ++w) addp += (w < wv) ? wsum[w] : 0;
    int incl = v + addp;
    int sstart = b * CAP + (incl - mycnt);   // exclusive start
    meta[b * B_KEYS + t] = make_int2(sstart, mycnt);
    kc[t] = sstart;
    __syncthreads();
    for (int i = t; i < cnt; i += 512) {
        unsigned it = items[i];
        int pos = atomicAdd(&kc[it >> 17], 1);
        csr[pos] = (int)(it & 0x1FFFFu);
    }
}

// ---------------- MFMA bf16 GEMM: fp8 row-major output [N][128] -------------
template <typename T>
__launch_bounds__(256)
__global__ void gemm_mfma_kernel(const T* __restrict__ X, const short* __restrict__ WT,
                                 unsigned char* __restrict__ Y, int nrows) {
    __shared__ __align__(16) short lds_w[128 * LDA];   // W^T; reused for C bytes
    int tid = threadIdx.x;
    int row0 = blockIdx.x * 64;

    {
        const uint4* w4 = (const uint4*)WT;
#pragma unroll
        for (int i = 0; i < 8; ++i) {
            int idx = tid + i * 256;          // 0..2047 = 128 rows x 16 uint4
            int n = idx >> 4, g = idx & 15;
            *(uint4*)(lds_w + n * LDA + g * 8) = w4[idx];
        }
    }

    int wv = tid >> 6, lane = tid & 63;
    int m = lane & 15, quad = lane >> 4;
    int row = row0 + wv * 16 + m;
    bool rowok = row < nrows;

    bf16x8 af[4];
    if constexpr (sizeof(T) == 4) {
        const float* xr = (const float*)X + (size_t)row * 128 + quad * 8;
#pragma unroll
        for (int k0 = 0; k0 < 4; ++k0) {
            float4 a0 = make_float4(0.f, 0.f, 0.f, 0.f), a1 = a0;
            if (rowok) {
                a0 = *(const float4*)(xr + k0 * 32);
                a1 = *(const float4*)(xr + k0 * 32 + 4);
            }
            bf16x8 f;
            f[0] = f2bf(a0.x); f[1] = f2bf(a0.y); f[2] = f2bf(a0.z); f[3] = f2bf(a0.w);
            f[4] = f2bf(a1.x); f[5] = f2bf(a1.y); f[6] = f2bf(a1.z); f[7] = f2bf(a1.w);
            af[k0] = f;
        }
    } else {
        const short* xr = (const short*)X + (size_t)row * 128 + quad * 8;
#pragma unroll
        for (int k0 = 0; k0 < 4; ++k0) {
            bf16x8 f = {0, 0, 0, 0, 0, 0, 0, 0};
            if (rowok) f = *(const bf16x8*)(xr + k0 * 32);
            af[k0] = f;
        }
    }
    __syncthreads();   // W staged

    f32x4 zero = {0.f, 0.f, 0.f, 0.f};
    f32x4 acc[8];
#pragma unroll
    for (int t8 = 0; t8 < 8; ++t8) acc[t8] = zero;

#pragma unroll
    for (int t8 = 0; t8 < 8; ++t8) {
        const short* brow = lds_w + (t8 * 16 + m) * LDA + quad * 8;
#pragma unroll
        for (int k0 = 0; k0 < 4; ++k0) {
            bf16x8 bf = *(const bf16x8*)(brow + k0 * 32);
            acc[t8] = __builtin_amdgcn_mfma_f32_16x16x32_bf16(af[k0], bf, acc[t8], 0, 0, 0);
        }
    }

    __syncthreads();   // W reads done; reuse LDS as fp8 C staging [64][LDC]
    char* lds_c = (char*)lds_w;
    // C/D layout: col = lane&15, row = quad*4 + reg
#pragma unroll
    for (int t8 = 0; t8 < 8; ++t8) {
#pragma unroll
        for (int r = 0; r < 4; ++r) {
            int crow = wv * 16 + quad * 4 + r;
            int ccol = t8 * 16 + m;
            lds_c[crow * LDC + ccol] = (char)f2fp8(acc[t8][r]);
        }
    }
    __syncthreads();
    // coalesced store: 64 rows x 8 uint4
#pragma unroll
    for (int i = 0; i < 2; ++i) {
        int idx = tid + i * 256;              // 0..511
        int r = idx >> 3, gq = idx & 7;
        if (row0 + r < nrows) {
            uint4 u = *(const uint4*)(lds_c + r * LDC + gq * 16);
            *(uint4*)(Y + (size_t)(row0 + r) * 128 + gq * 16) = u;
        }
    }
}

// ---------------- fp8 segment gather-sum ----------------
// MODE 0: edge agg (scale only) -> fp8 rows
// MODE 1: node agg + bias + relu -> bf16 rows (GEMM-2 input stays bf16)
// MODE 2: node agg + bias + relu -> per-block 128-col partials (f32)
//
// 8 lanes per segment (fl = lane&7 owns features fl*16..+15, 16 B), 8 segs
// per wave, 32 segs/block (3125 x 32 = 100000 exact; 32 | 512 so the block's
// csr range is contiguous -> LDS-staged coalesced, touched once). Each row
// gather = 8 lanes x 16 B = ONE 128-B line transaction.
template <int MODE>
__launch_bounds__(256)
__global__ void agg_fp8_kernel(const unsigned char* __restrict__ src, const int2* __restrict__ meta,
                               const int* __restrict__ col, const float* __restrict__ bias,
                               void* __restrict__ dstv) {
    __shared__ int lds_col[LDSCOL];
    int g = blockIdx.x;
    int tid = threadIdx.x;
    int wid = tid >> 6, lane = tid & 63;
    int fl = lane & 7, sub = lane >> 3;
    int seg = g * 32 + wid * 8 + sub;          // always < N_NODES

    int gbase = g * 32;
    int2 mF = meta[gbase];
    int2 mL = meta[gbase + 31];
    int r0 = mF.x;
    int total = mL.x + mL.y - r0;
    if (total > LDSCOL) total = LDSCOL;        // +22 sigma, never in practice
    for (int i = tid; i < total; i += 256) lds_col[i] = col[r0 + i];

    int2 mt = meta[seg];
    int ls = mt.x - r0;
    int cnt = mt.y;
    if (ls < 0 || ls + cnt > total) cnt = 0;   // consistency with the clamp
    __syncthreads();

    const unsigned char* sp8 = src + fl * 16;
    float acc[16];
#pragma unroll
    for (int i = 0; i < 16; ++i) acc[i] = 0.f;

    int j = 0;
    for (; j + 2 <= cnt; j += 2) {             // 2-deep: both lines in flight
        int i0 = lds_col[ls + j];
        int i1 = lds_col[ls + j + 1];
        uint4 u0 = *(const uint4*)(sp8 + (size_t)i0 * 128);
        uint4 u1 = *(const uint4*)(sp8 + (size_t)i1 * 128);
        accum16(acc, u0);
        accum16(acc, u1);
    }
    if (j < cnt) {
        int i0 = lds_col[ls + j];
        uint4 u0 = *(const uint4*)(sp8 + (size_t)i0 * 128);
        accum16(acc, u0);
    }

    float sc = cnt ? 1.0f / (float)cnt : 0.0f;
    if constexpr (MODE == 0) {
        unsigned char* dst = (unsigned char*)dstv;
        uint4 o;
        o.x = pack4fp8(acc[0] * sc,  acc[1] * sc,  acc[2] * sc,  acc[3] * sc);
        o.y = pack4fp8(acc[4] * sc,  acc[5] * sc,  acc[6] * sc,  acc[7] * sc);
        o.z = pack4fp8(acc[8] * sc,  acc[9] * sc,  acc[10] * sc, acc[11] * sc);
        o.w = pack4fp8(acc[12] * sc, acc[13] * sc, acc[14] * sc, acc[15] * sc);
        *(uint4*)(dst + (size_t)seg * 128 + fl * 16) = o;
    } else {
        const float4* b4 = (const float4*)(bias + fl * 16);
        float4 b0 = b4[0], b1 = b4[1], b2 = b4[2], b3 = b4[3];
        float v[16];
        v[0]  = fmaxf(fmaf(acc[0],  sc, b0.x), 0.f);
        v[1]  = fmaxf(fmaf(acc[1],  sc, b0.y), 0.f);
        v[2]  = fmaxf(fmaf(acc[2],  sc, b0.z), 0.f);
        v[3]  = fmaxf(fmaf(acc[3],  sc, b0.w), 0.f);
        v[4]  = fmaxf(fmaf(acc[4],  sc, b1.x), 0.f);
        v[5]  = fmaxf(fmaf(acc[5],  sc, b1.y), 0.f);
        v[6]  = fmaxf(fmaf(acc[6],  sc, b1.z), 0.f);
        v[7]  = fmaxf(fmaf(acc[7],  sc, b1.w), 0.f);
        v[8]  = fmaxf(fmaf(acc[8],  sc, b2.x), 0.f);
        v[9]  = fmaxf(fmaf(acc[9],  sc, b2.y), 0.f);
        v[10] = fmaxf(fmaf(acc[10], sc, b2.z), 0.f);
        v[11] = fmaxf(fmaf(acc[11], sc, b2.w), 0.f);
        v[12] = fmaxf(fmaf(acc[12], sc, b3.x), 0.f);
        v[13] = fmaxf(fmaf(acc[13], sc, b3.y), 0.f);
        v[14] = fmaxf(fmaf(acc[14], sc, b3.z), 0.f);
        v[15] = fmaxf(fmaf(acc[15], sc, b3.w), 0.f);
        if constexpr (MODE == 1) {
            char* dst = (char*)dstv;
            uint4 oA, oB;
            oA.x = packbf2(v[0], v[1]);   oA.y = packbf2(v[2], v[3]);
            oA.z = packbf2(v[4], v[5]);   oA.w = packbf2(v[6], v[7]);
            oB.x = packbf2(v[8], v[9]);   oB.y = packbf2(v[10], v[11]);
            oB.z = packbf2(v[12], v[13]); oB.w = packbf2(v[14], v[15]);
            *(uint4*)(dst + (size_t)seg * 256 + fl * 32) = oA;
            *(uint4*)(dst + (size_t)seg * 256 + fl * 32 + 16) = oB;
        } else {
            // reduce across the 8 segs in this wave (lane bits 3,4,5)
#pragma unroll
            for (int i = 0; i < 16; ++i) {
                v[i] += __shfl_xor(v[i], 8);
                v[i] += __shfl_xor(v[i], 16);
                v[i] += __shfl_xor(v[i], 32);
            }
            __shared__ float spd[4][128];
            if (sub == 0) {
#pragma unroll
                for (int i = 0; i < 16; ++i) spd[wid][fl * 16 + i] = v[i];
            }
            __syncthreads();
            if (tid < 128) {
                float r = spd[0][tid] + spd[1][tid] + spd[2][tid] + spd[3][tid];
                ((float*)dstv)[(size_t)g * 128 + tid] = r;
            }
        }
    }
}

// ---------------- mean reduction, coalesced two-stage ----------------
__launch_bounds__(256)
__global__ void mean_stage1_kernel(const float* __restrict__ partials, float* __restrict__ partials2,
                                   int nrows) {
    __shared__ __align__(16) float4 s4[256];
    int t = threadIdx.x;
    int c4 = t & 31, r8 = t >> 5;
    float4 a = make_float4(0.f, 0.f, 0.f, 0.f);
    for (int r = blockIdx.x * 8 + r8; r < nrows; r += 256 * 8) {
        float4 v = ((const float4*)partials)[(size_t)r * 32 + c4];
        a.x += v.x; a.y += v.y; a.z += v.z; a.w += v.w;
    }
    s4[t] = a;
    __syncthreads();
    if (t < 32) {
        float4 v = s4[t];
#pragma unroll
        for (int i = 1; i < 8; ++i) {
            float4 u = s4[t + 32 * i];
            v.x += u.x; v.y += u.y; v.z += u.z; v.w += u.w;
        }
        ((float4*)partials2)[(size_t)blockIdx.x * 32 + t] = v;
    }
}

__launch_bounds__(256)
__global__ void mean_stage2_kernel(const float* __restrict__ partials2, float* __restrict__ out) {
    __shared__ __align__(16) float4 s4[256];
    int t = threadIdx.x;
    int c4 = t & 31, r8 = t >> 5;
    float4 a = make_float4(0.f, 0.f, 0.f, 0.f);
    for (int r = r8; r < 256; r += 8) {
        float4 v = ((const float4*)partials2)[(size_t)r * 32 + c4];
        a.x += v.x; a.y += v.y; a.z += v.z; a.w += v.w;
    }
    s4[t] = a;
    __syncthreads();
    if (t < 32) {
        float4 v = s4[t];
#pragma unroll
        for (int i = 1; i < 8; ++i) {
            float4 u = s4[t + 32 * i];
            v.x += u.x; v.y += u.y; v.z += u.z; v.w += u.w;
        }
        const float inv = 1.0f / (float)N_NODES;
        v.x *= inv; v.y *= inv; v.z *= inv; v.w *= inv;
        ((float4*)out)[t] = v;
    }
}

// ---------------- launch ----------------
extern "C" void kernel_launch(void* const* d_in, const int* in_sizes, int n_in,
                              void* d_out, int out_size, void* d_ws, size_t ws_size,
                              hipStream_t stream) {
    const float* x  = (const float*)d_in[0];
    const int*   ei = (const int*)d_in[1];
    const float* w1 = (const float*)d_in[2];
    const float* b1 = (const float*)d_in[3];
    const float* w2 = (const float*)d_in[4];
    const float* b2 = (const float*)d_in[5];
    float* out = (float*)d_out;
    const int* nidx = ei;
    const int* hidx = ei + N_INC;

    char* wsp = (char*)d_ws;
    size_t off = 0;
    auto alloc = [&](size_t bytes) -> void* {
        void* p = wsp + off;
        off += (bytes + 255) & ~(size_t)255;
        return p;
    };

    unsigned char* A = (unsigned char*)alloc((size_t)N_NODES * 128);   // fp8 gemm out (reused L2)
    unsigned char* E = (unsigned char*)alloc((size_t)N_NODES * 128);   // fp8 edge means (reused)
    char* O          = (char*)alloc((size_t)N_NODES * 128 * 2);        // bf16 out1 (gemm-2 input)
    unsigned* bin_e  = (unsigned*)alloc((size_t)NBUCK * CAP * 4);
    unsigned* bin_n  = (unsigned*)alloc((size_t)NBUCK * CAP * 4);
    int* csr_e       = (int*)alloc((size_t)NBUCK * CAP * 4);
    int* csr_n       = (int*)alloc((size_t)NBUCK * CAP * 4);
    float* partials  = (float*)alloc((size_t)GAGG * 128 * 4);
    float* partials2 = (float*)alloc((size_t)256 * 128 * 4);
    int2* meta_e     = (int2*)alloc((size_t)NBUCK * B_KEYS * 8);
    int2* meta_n     = (int2*)alloc((size_t)NBUCK * B_KEYS * 8);
    short* WT1       = (short*)alloc((size_t)128 * 128 * 2);
    short* WT2       = (short*)alloc((size_t)128 * 128 * 2);
    int* gcnt        = (int*)alloc((size_t)2 * NBUCK * 4);
    int* gcnt_e = gcnt;
    int* gcnt_n = gcnt + NBUCK;

    wt_kernel<<<128, 256, 0, stream>>>(w1, w2, WT1, WT2, gcnt);
    binA_kernel<<<NBLKA, 256, 0, stream>>>(nidx, hidx, gcnt_e, gcnt_n, bin_e, bin_n);
    binB2_kernel<<<2 * NBUCK, 512, 0, stream>>>(gcnt_e, bin_e, csr_e, meta_e,
                                                gcnt_n, bin_n, csr_n, meta_n);

    int gGemm = (N_NODES + 63) / 64;

    // layer 1
    gemm_mfma_kernel<float><<<gGemm, 256, 0, stream>>>(x, WT1, A, N_NODES);
    agg_fp8_kernel<0><<<GAGG, 256, 0, stream>>>(A, meta_e, csr_e, nullptr, E);
    agg_fp8_kernel<1><<<GAGG, 256, 0, stream>>>(E, meta_n, csr_n, b1, O);
    // layer 2
    gemm_mfma_kernel<__hip_bfloat16><<<gGemm, 256, 0, stream>>>((const __hip_bfloat16*)O, WT2, A, N_NODES);
    agg_fp8_kernel<0><<<GAGG, 256, 0, stream>>>(A, meta_e, csr_e, nullptr, E);
    agg_fp8_kernel<2><<<GAGG, 256, 0, stream>>>(E, meta_n, csr_n, b2, partials);
    mean_stage1_kernel<<<256, 256, 0, stream>>>(partials, partials2, GAGG);
    mean_stage2_kernel<<<1, 256, 0, stream>>>(partials2, out);
}

// Round 9
// 300.603 us; speedup vs baseline: 1.5177x; 1.0105x over previous
//
#include <hip/hip_runtime.h>
#include <hip/hip_bf16.h>

#define N_NODES 100000
#define N_HEDGES 100000
#define N_INC 1600000
#define D 128

#define B_KEYS 512            // keys per bucket
#define NBUCK 196             // ceil(100000/512)
#define CAP 10240             // bucket capacity (mean 8192, sigma ~90)
#define CHUNK 4096            // 16 items per thread, register-resident
#define NBLKA ((N_INC + CHUNK - 1) / CHUNK)   // 391

#define LDA 136               // padded bf16 row stride for GEMM W tile
#define LDC 144               // padded fp8 byte row stride for GEMM C staging

// fp8 row-major gather layout: row = 128 features x 1 B = exactly one 128-B
// line; 8 consecutive lanes x 16 B coalesce to ONE transaction per row.
// Round-8 proof: 456 -> 304 us, absmax unchanged at the bf16 floor (RNE fp8
// noise washes out in the segment means + 100K-node mean).
#define GAGG 3125             // 100000 / 32 segs per block (exact)
#define LDSCOL 1024           // staged index run per block (mean 512, +22 sigma)

typedef __attribute__((ext_vector_type(8))) short bf16x8;
typedef __attribute__((ext_vector_type(4))) float f32x4;
typedef __attribute__((ext_vector_type(2))) float f32x2;

#if __has_builtin(__builtin_amdgcn_cvt_pk_f32_fp8) && __has_builtin(__builtin_amdgcn_cvt_pk_fp8_f32)
#define FP8_HW 1
#else
#define FP8_HW 0
#endif

__device__ __forceinline__ short f2bf(float v) {
    __hip_bfloat16 b = __float2bfloat16(v);
    return *(short*)&b;
}
__device__ __forceinline__ unsigned packbf2(float x, float y) {
    __hip_bfloat162 p = __float22bfloat162_rn(make_float2(x, y));
    return *(unsigned*)&p;
}

// ---------------- fp8 e4m3 helpers (HW cvt with guarded SW fallback) --------
#if !FP8_HW
__device__ __forceinline__ float fp8dec(unsigned b) {
    unsigned em = b & 0x7Fu;
    float mag = (em >= 8u)
        ? __uint_as_float((((em >> 3) + 120u) << 23) | ((em & 7u) << 20))
        : (float)em * 0x1.0p-9f;                 // denormal: m * 2^-9
    return (b & 0x80u) ? -mag : mag;
}
#endif

__device__ __forceinline__ unsigned char f2fp8(float v) {
#if FP8_HW
    return (unsigned char)(__builtin_amdgcn_cvt_pk_fp8_f32(v, v, 0, false) & 0xFF);
#else
    unsigned s = (__float_as_uint(v) >> 24) & 0x80u;
    float a = fabsf(v);
    a = fminf(a, 448.0f);
    unsigned q;
    if (a < 0x1.0p-6f) {
        q = (unsigned)__float2int_rn(a * 512.0f);       // denormal, RNE
    } else {
        unsigned u = __float_as_uint(a * 0x1.0p-120f);  // exponent re-bias
        unsigned rest = u & 0xFFFFFu;
        q = u >> 20;
        q += (rest > 0x80000u) || (rest == 0x80000u && (q & 1u));  // RNE
    }
    if (q > 0x7Eu) q = 0x7Eu;                           // cap at 448, avoid NaN
    return (unsigned char)(s | q);
#endif
}

__device__ __forceinline__ unsigned pack4fp8(float a, float b, float c, float d) {
#if FP8_HW
    unsigned v = (unsigned)__builtin_amdgcn_cvt_pk_fp8_f32(a, b, 0, false);
    v = (unsigned)__builtin_amdgcn_cvt_pk_fp8_f32(c, d, (int)v, true);
    return v;
#else
    return (unsigned)f2fp8(a) | ((unsigned)f2fp8(b) << 8) |
           ((unsigned)f2fp8(c) << 16) | ((unsigned)f2fp8(d) << 24);
#endif
}

__device__ __forceinline__ void accum16(float* a, uint4 u) {
#if FP8_HW
    f32x2 p;
    p = __builtin_amdgcn_cvt_pk_f32_fp8((int)u.x, false); a[0]  += p.x; a[1]  += p.y;
    p = __builtin_amdgcn_cvt_pk_f32_fp8((int)u.x, true);  a[2]  += p.x; a[3]  += p.y;
    p = __builtin_amdgcn_cvt_pk_f32_fp8((int)u.y, false); a[4]  += p.x; a[5]  += p.y;
    p = __builtin_amdgcn_cvt_pk_f32_fp8((int)u.y, true);  a[6]  += p.x; a[7]  += p.y;
    p = __builtin_amdgcn_cvt_pk_f32_fp8((int)u.z, false); a[8]  += p.x; a[9]  += p.y;
    p = __builtin_amdgcn_cvt_pk_f32_fp8((int)u.z, true);  a[10] += p.x; a[11] += p.y;
    p = __builtin_amdgcn_cvt_pk_f32_fp8((int)u.w, false); a[12] += p.x; a[13] += p.y;
    p = __builtin_amdgcn_cvt_pk_f32_fp8((int)u.w, true);  a[14] += p.x; a[15] += p.y;
#else
    unsigned w[4] = {u.x, u.y, u.z, u.w};
#pragma unroll
    for (int d = 0; d < 4; ++d) {
        a[d*4+0] += fp8dec(w[d] & 0xFF);
        a[d*4+1] += fp8dec((w[d] >> 8) & 0xFF);
        a[d*4+2] += fp8dec((w[d] >> 16) & 0xFF);
        a[d*4+3] += fp8dec(w[d] >> 24);
    }
#endif
}

// ---------------- W transpose + bf16 convert (once per call) ----------------
__global__ void wt_kernel(const float* __restrict__ W1, const float* __restrict__ W2,
                          short* __restrict__ WT1, short* __restrict__ WT2,
                          int* __restrict__ gcnt) {
    if (blockIdx.x == 0) {
        for (int i = threadIdx.x; i < 2 * NBUCK; i += 256) gcnt[i] = 0;
    }
    int idx = blockIdx.x * 256 + threadIdx.x;     // 0..32767
    int sel = idx >> 14;
    int li = idx & 16383;
    int n = li >> 7, k = li & 127;
    const float* src = sel ? W2 : W1;
    short* dst = sel ? WT2 : WT1;
    dst[li] = f2bf(src[k * 128 + n]);
}

// ---------------- Phase A: bucket partition, register-resident chunk ----------------
// int4-vectorized edge_index loads (N_INC % 4 == 0, CHUNK % 1024 == 0).
__launch_bounds__(256)
__global__ void binA_kernel(const int* __restrict__ nidx, const int* __restrict__ hidx,
                            int* __restrict__ gcnt_e, int* __restrict__ gcnt_n,
                            unsigned* __restrict__ bin_e, unsigned* __restrict__ bin_n) {
    __shared__ int hist_e[NBUCK], hist_n[NBUCK], base_e[NBUCK], base_n[NBUCK];
    int t = threadIdx.x;
    int items_h[16], items_n[16];
    int start = blockIdx.x * CHUNK;
    {
        const int4* h4 = (const int4*)hidx;
        const int4* n4 = (const int4*)nidx;
        int base4 = start >> 2;               // int4 index of block start
#pragma unroll
        for (int k = 0; k < 4; ++k) {
            int q = base4 + t + k * 256;
            bool ok = q < (N_INC >> 2);
            int4 vh = ok ? h4[q] : make_int4(-1, -1, -1, -1);
            int4 vn = ok ? n4[q] : make_int4(-1, -1, -1, -1);
            items_h[k * 4 + 0] = vh.x; items_h[k * 4 + 1] = vh.y;
            items_h[k * 4 + 2] = vh.z; items_h[k * 4 + 3] = vh.w;
            items_n[k * 4 + 0] = vn.x; items_n[k * 4 + 1] = vn.y;
            items_n[k * 4 + 2] = vn.z; items_n[k * 4 + 3] = vn.w;
        }
    }
    for (int b = t; b < NBUCK; b += 256) { hist_e[b] = 0; hist_n[b] = 0; }
    __syncthreads();
#pragma unroll
    for (int k = 0; k < 16; ++k) {
        if (items_h[k] >= 0) {
            atomicAdd(&hist_e[items_h[k] >> 9], 1);
            atomicAdd(&hist_n[items_n[k] >> 9], 1);
        }
    }
    __syncthreads();
    for (int b = t; b < NBUCK; b += 256) {
        base_e[b] = atomicAdd(&gcnt_e[b], hist_e[b]);
        base_n[b] = atomicAdd(&gcnt_n[b], hist_n[b]);
        hist_e[b] = 0; hist_n[b] = 0;
    }
    __syncthreads();
#pragma unroll
    for (int k = 0; k < 16; ++k) {
        if (items_h[k] >= 0) {
            int h = items_h[k], n = items_n[k];
            int be = h >> 9, bn = n >> 9;
            int oe = base_e[be] + atomicAdd(&hist_e[be], 1);
            if (oe >= 0 && oe < CAP) bin_e[(size_t)be * CAP + oe] = ((unsigned)(h & 511) << 17) | (unsigned)n;
            int on = base_n[bn] + atomicAdd(&hist_n[bn], 1);
            if (on >= 0 && on < CAP) bin_n[(size_t)bn * CAP + on] = ((unsigned)(n & 511) << 17) | (unsigned)h;
        }
    }
}

// ---------------- Phase B: per-bucket counting sort, wave-shuffle scan ----------
__launch_bounds__(512)
__global__ void binB2_kernel(const int* __restrict__ gcnt_e, const unsigned* __restrict__ bin_e,
                             int* __restrict__ csr_e, int2* __restrict__ meta_e,
                             const int* __restrict__ gcnt_n, const unsigned* __restrict__ bin_n,
                             int* __restrict__ csr_n, int2* __restrict__ meta_n) {
    __shared__ int kc[B_KEYS];
    __shared__ int wsum[8];
    int b = blockIdx.x;
    const int* gcnt;  const unsigned* bin;  int* csr;  int2* meta;
    if (b < NBUCK) { gcnt = gcnt_e; bin = bin_e; csr = csr_e; meta = meta_e; }
    else { b -= NBUCK; gcnt = gcnt_n; bin = bin_n; csr = csr_n; meta = meta_n; }
    int t = threadIdx.x;
    int lane = t & 63, wv = t >> 6;
    int cnt = gcnt[b];
    if (cnt > CAP) cnt = CAP;
    kc[t] = 0;
    __syncthreads();
    const unsigned* items = bin + (size_t)b * CAP;
    for (int i = t; i < cnt; i += 512) atomicAdd(&kc[items[i] >> 17], 1);
    __syncthreads();
    int mycnt = kc[t];
    int v = mycnt;
#pragma unroll
    for (int off = 1; off < 64; off <<= 1) {
        int u = __shfl_up(v, off);
        if (lane >= off) v += u;
    }
    if (lane == 63) wsum[wv] = v;
    __syncthreads();
    int addp = 0;
#pragma unroll
    for (int w = 0; w < 7; ++w) addp += (w < wv) ? wsum[w] : 0;
    int incl = v + addp;
    int sstart = b * CAP + (incl - mycnt);   // exclusive start
    meta[b * B_KEYS + t] = make_int2(sstart, mycnt);
    kc[t] = sstart;
    __syncthreads();
    for (int i = t; i < cnt; i += 512) {
        unsigned it = items[i];
        int pos = atomicAdd(&kc[it >> 17], 1);
        csr[pos] = (int)(it & 0x1FFFFu);
    }
}

// ---------------- MFMA bf16 GEMM: fp8 row-major output [N][128] -------------
template <typename T>
__launch_bounds__(256)
__global__ void gemm_mfma_kernel(const T* __restrict__ X, const short* __restrict__ WT,
                                 unsigned char* __restrict__ Y, int nrows) {
    __shared__ __align__(16) short lds_w[128 * LDA];   // W^T; reused for C bytes
    int tid = threadIdx.x;
    int row0 = blockIdx.x * 64;

    {
        const uint4* w4 = (const uint4*)WT;
#pragma unroll
        for (int i = 0; i < 8; ++i) {
            int idx = tid + i * 256;          // 0..2047 = 128 rows x 16 uint4
            int n = idx >> 4, g = idx & 15;
            *(uint4*)(lds_w + n * LDA + g * 8) = w4[idx];
        }
    }

    int wv = tid >> 6, lane = tid & 63;
    int m = lane & 15, quad = lane >> 4;
    int row = row0 + wv * 16 + m;
    bool rowok = row < nrows;

    bf16x8 af[4];
    if constexpr (sizeof(T) == 4) {
        const float* xr = (const float*)X + (size_t)row * 128 + quad * 8;
#pragma unroll
        for (int k0 = 0; k0 < 4; ++k0) {
            float4 a0 = make_float4(0.f, 0.f, 0.f, 0.f), a1 = a0;
            if (rowok) {
                a0 = *(const float4*)(xr + k0 * 32);
                a1 = *(const float4*)(xr + k0 * 32 + 4);
            }
            bf16x8 f;
            f[0] = f2bf(a0.x); f[1] = f2bf(a0.y); f[2] = f2bf(a0.z); f[3] = f2bf(a0.w);
            f[4] = f2bf(a1.x); f[5] = f2bf(a1.y); f[6] = f2bf(a1.z); f[7] = f2bf(a1.w);
            af[k0] = f;
        }
    } else {
        const short* xr = (const short*)X + (size_t)row * 128 + quad * 8;
#pragma unroll
        for (int k0 = 0; k0 < 4; ++k0) {
            bf16x8 f = {0, 0, 0, 0, 0, 0, 0, 0};
            if (rowok) f = *(const bf16x8*)(xr + k0 * 32);
            af[k0] = f;
        }
    }
    __syncthreads();   // W staged

    f32x4 zero = {0.f, 0.f, 0.f, 0.f};
    f32x4 acc[8];
#pragma unroll
    for (int t8 = 0; t8 < 8; ++t8) acc[t8] = zero;

#pragma unroll
    for (int t8 = 0; t8 < 8; ++t8) {
        const short* brow = lds_w + (t8 * 16 + m) * LDA + quad * 8;
#pragma unroll
        for (int k0 = 0; k0 < 4; ++k0) {
            bf16x8 bf = *(const bf16x8*)(brow + k0 * 32);
            acc[t8] = __builtin_amdgcn_mfma_f32_16x16x32_bf16(af[k0], bf, acc[t8], 0, 0, 0);
        }
    }

    __syncthreads();   // W reads done; reuse LDS as fp8 C staging [64][LDC]
    char* lds_c = (char*)lds_w;
    // C/D layout: col = lane&15, row = quad*4 + reg
#pragma unroll
    for (int t8 = 0; t8 < 8; ++t8) {
#pragma unroll
        for (int r = 0; r < 4; ++r) {
            int crow = wv * 16 + quad * 4 + r;
            int ccol = t8 * 16 + m;
            lds_c[crow * LDC + ccol] = (char)f2fp8(acc[t8][r]);
        }
    }
    __syncthreads();
    // coalesced store: 64 rows x 8 uint4
#pragma unroll
    for (int i = 0; i < 2; ++i) {
        int idx = tid + i * 256;              // 0..511
        int r = idx >> 3, gq = idx & 7;
        if (row0 + r < nrows) {
            uint4 u = *(const uint4*)(lds_c + r * LDC + gq * 16);
            *(uint4*)(Y + (size_t)(row0 + r) * 128 + gq * 16) = u;
        }
    }
}

// ---------------- fp8 segment gather-sum ----------------
// MODE 0: edge agg (scale only) -> fp8 rows
// MODE 1: node agg + bias + relu -> bf16 rows (GEMM-2 input stays bf16)
// MODE 2: node agg + bias + relu -> per-block 128-col partials (f32)
//
// 8 lanes per segment (fl = lane&7 owns features fl*16..+15, 16 B), 8 segs
// per wave, 32 segs/block. Each row gather = 8 lanes x 16 B = ONE 128-B line
// transaction. Round-9: 4-deep inner pipeline — compiler's counted vmcnt
// waits leave 3 loads in flight at first consume, halving the serial
// LLC-latency chain (8 -> 4 exposed steps per segment).
template <int MODE>
__launch_bounds__(256)
__global__ void agg_fp8_kernel(const unsigned char* __restrict__ src, const int2* __restrict__ meta,
                               const int* __restrict__ col, const float* __restrict__ bias,
                               void* __restrict__ dstv) {
    __shared__ int lds_col[LDSCOL];
    int g = blockIdx.x;
    int tid = threadIdx.x;
    int wid = tid >> 6, lane = tid & 63;
    int fl = lane & 7, sub = lane >> 3;
    int seg = g * 32 + wid * 8 + sub;          // always < N_NODES

    int gbase = g * 32;
    int2 mF = meta[gbase];
    int2 mL = meta[gbase + 31];
    int r0 = mF.x;
    int total = mL.x + mL.y - r0;
    if (total > LDSCOL) total = LDSCOL;        // +22 sigma, never in practice
    for (int i = tid; i < total; i += 256) lds_col[i] = col[r0 + i];

    int2 mt = meta[seg];
    int ls = mt.x - r0;
    int cnt = mt.y;
    if (ls < 0 || ls + cnt > total) cnt = 0;   // consistency with the clamp
    __syncthreads();

    const unsigned char* sp8 = src + fl * 16;
    float acc[16];
#pragma unroll
    for (int i = 0; i < 16; ++i) acc[i] = 0.f;

    int j = 0;
    for (; j + 4 <= cnt; j += 4) {             // 4-deep: 4 lines in flight
        int i0 = lds_col[ls + j];
        int i1 = lds_col[ls + j + 1];
        int i2 = lds_col[ls + j + 2];
        int i3 = lds_col[ls + j + 3];
        uint4 u0 = *(const uint4*)(sp8 + (size_t)i0 * 128);
        uint4 u1 = *(const uint4*)(sp8 + (size_t)i1 * 128);
        uint4 u2 = *(const uint4*)(sp8 + (size_t)i2 * 128);
        uint4 u3 = *(const uint4*)(sp8 + (size_t)i3 * 128);
        accum16(acc, u0);
        accum16(acc, u1);
        accum16(acc, u2);
        accum16(acc, u3);
    }
    if (j + 2 <= cnt) {
        int i0 = lds_col[ls + j];
        int i1 = lds_col[ls + j + 1];
        uint4 u0 = *(const uint4*)(sp8 + (size_t)i0 * 128);
        uint4 u1 = *(const uint4*)(sp8 + (size_t)i1 * 128);
        accum16(acc, u0);
        accum16(acc, u1);
        j += 2;
    }
    if (j < cnt) {
        int i0 = lds_col[ls + j];
        uint4 u0 = *(const uint4*)(sp8 + (size_t)i0 * 128);
        accum16(acc, u0);
    }

    float sc = cnt ? 1.0f / (float)cnt : 0.0f;
    if constexpr (MODE == 0) {
        unsigned char* dst = (unsigned char*)dstv;
        uint4 o;
        o.x = pack4fp8(acc[0] * sc,  acc[1] * sc,  acc[2] * sc,  acc[3] * sc);
        o.y = pack4fp8(acc[4] * sc,  acc[5] * sc,  acc[6] * sc,  acc[7] * sc);
        o.z = pack4fp8(acc[8] * sc,  acc[9] * sc,  acc[10] * sc, acc[11] * sc);
        o.w = pack4fp8(acc[12] * sc, acc[13] * sc, acc[14] * sc, acc[15] * sc);
        *(uint4*)(dst + (size_t)seg * 128 + fl * 16) = o;
    } else {
        const float4* b4 = (const float4*)(bias + fl * 16);
        float4 b0 = b4[0], b1 = b4[1], b2 = b4[2], b3 = b4[3];
        float v[16];
        v[0]  = fmaxf(fmaf(acc[0],  sc, b0.x), 0.f);
        v[1]  = fmaxf(fmaf(acc[1],  sc, b0.y), 0.f);
        v[2]  = fmaxf(fmaf(acc[2],  sc, b0.z), 0.f);
        v[3]  = fmaxf(fmaf(acc[3],  sc, b0.w), 0.f);
        v[4]  = fmaxf(fmaf(acc[4],  sc, b1.x), 0.f);
        v[5]  = fmaxf(fmaf(acc[5],  sc, b1.y), 0.f);
        v[6]  = fmaxf(fmaf(acc[6],  sc, b1.z), 0.f);
        v[7]  = fmaxf(fmaf(acc[7],  sc, b1.w), 0.f);
        v[8]  = fmaxf(fmaf(acc[8],  sc, b2.x), 0.f);
        v[9]  = fmaxf(fmaf(acc[9],  sc, b2.y), 0.f);
        v[10] = fmaxf(fmaf(acc[10], sc, b2.z), 0.f);
        v[11] = fmaxf(fmaf(acc[11], sc, b2.w), 0.f);
        v[12] = fmaxf(fmaf(acc[12], sc, b3.x), 0.f);
        v[13] = fmaxf(fmaf(acc[13], sc, b3.y), 0.f);
        v[14] = fmaxf(fmaf(acc[14], sc, b3.z), 0.f);
        v[15] = fmaxf(fmaf(acc[15], sc, b3.w), 0.f);
        if constexpr (MODE == 1) {
            char* dst = (char*)dstv;
            uint4 oA, oB;
            oA.x = packbf2(v[0], v[1]);   oA.y = packbf2(v[2], v[3]);
            oA.z = packbf2(v[4], v[5]);   oA.w = packbf2(v[6], v[7]);
            oB.x = packbf2(v[8], v[9]);   oB.y = packbf2(v[10], v[11]);
            oB.z = packbf2(v[12], v[13]); oB.w = packbf2(v[14], v[15]);
            *(uint4*)(dst + (size_t)seg * 256 + fl * 32) = oA;
            *(uint4*)(dst + (size_t)seg * 256 + fl * 32 + 16) = oB;
        } else {
            // reduce across the 8 segs in this wave (lane bits 3,4,5)
#pragma unroll
            for (int i = 0; i < 16; ++i) {
                v[i] += __shfl_xor(v[i], 8);
                v[i] += __shfl_xor(v[i], 16);
                v[i] += __shfl_xor(v[i], 32);
            }
            __shared__ float spd[4][128];
            if (sub == 0) {
#pragma unroll
                for (int i = 0; i < 16; ++i) spd[wid][fl * 16 + i] = v[i];
            }
            __syncthreads();
            if (tid < 128) {
                float r = spd[0][tid] + spd[1][tid] + spd[2][tid] + spd[3][tid];
                ((float*)dstv)[(size_t)g * 128 + tid] = r;
            }
        }
    }
}

// ---------------- mean reduction, coalesced two-stage ----------------
__launch_bounds__(256)
__global__ void mean_stage1_kernel(const float* __restrict__ partials, float* __restrict__ partials2,
                                   int nrows) {
    __shared__ __align__(16) float4 s4[256];
    int t = threadIdx.x;
    int c4 = t & 31, r8 = t >> 5;
    float4 a = make_float4(0.f, 0.f, 0.f, 0.f);
    for (int r = blockIdx.x * 8 + r8; r < nrows; r += 256 * 8) {
        float4 v = ((const float4*)partials)[(size_t)r * 32 + c4];
        a.x += v.x; a.y += v.y; a.z += v.z; a.w += v.w;
    }
    s4[t] = a;
    __syncthreads();
    if (t < 32) {
        float4 v = s4[t];
#pragma unroll
        for (int i = 1; i < 8; ++i) {
            float4 u = s4[t + 32 * i];
            v.x += u.x; v.y += u.y; v.z += u.z; v.w += u.w;
        }
        ((float4*)partials2)[(size_t)blockIdx.x * 32 + t] = v;
    }
}

__launch_bounds__(256)
__global__ void mean_stage2_kernel(const float* __restrict__ partials2, float* __restrict__ out) {
    __shared__ __align__(16) float4 s4[256];
    int t = threadIdx.x;
    int c4 = t & 31, r8 = t >> 5;
    float4 a = make_float4(0.f, 0.f, 0.f, 0.f);
    for (int r = r8; r < 256; r += 8) {
        float4 v = ((const float4*)partials2)[(size_t)r * 32 + c4];
        a.x += v.x; a.y += v.y; a.z += v.z; a.w += v.w;
    }
    s4[t] = a;
    __syncthreads();
    if (t < 32) {
        float4 v = s4[t];
#pragma unroll
        for (int i = 1; i < 8; ++i) {
            float4 u = s4[t + 32 * i];
            v.x += u.x; v.y += u.y; v.z += u.z; v.w += u.w;
        }
        const float inv = 1.0f / (float)N_NODES;
        v.x *= inv; v.y *= inv; v.z *= inv; v.w *= inv;
        ((float4*)out)[t] = v;
    }
}

// ---------------- launch ----------------
extern "C" void kernel_launch(void* const* d_in, const int* in_sizes, int n_in,
                              void* d_out, int out_size, void* d_ws, size_t ws_size,
                              hipStream_t stream) {
    const float* x  = (const float*)d_in[0];
    const int*   ei = (const int*)d_in[1];
    const float* w1 = (const float*)d_in[2];
    const float* b1 = (const float*)d_in[3];
    const float* w2 = (const float*)d_in[4];
    const float* b2 = (const float*)d_in[5];
    float* out = (float*)d_out;
    const int* nidx = ei;
    const int* hidx = ei + N_INC;

    char* wsp = (char*)d_ws;
    size_t off = 0;
    auto alloc = [&](size_t bytes) -> void* {
        void* p = wsp + off;
        off += (bytes + 255) & ~(size_t)255;
        return p;
    };

    unsigned char* A = (unsigned char*)alloc((size_t)N_NODES * 128);   // fp8 gemm out
    unsigned char* E = (unsigned char*)alloc((size_t)N_NODES * 128);   // fp8 edge means
    char* O          = (char*)alloc((size_t)N_NODES * 128 * 2);        // bf16 out1 (gemm-2 input)
    unsigned* bin_e  = (unsigned*)alloc((size_t)NBUCK * CAP * 4);
    unsigned* bin_n  = (unsigned*)alloc((size_t)NBUCK * CAP * 4);
    int* csr_e       = (int*)alloc((size_t)NBUCK * CAP * 4);
    int* csr_n       = (int*)alloc((size_t)NBUCK * CAP * 4);
    float* partials  = (float*)alloc((size_t)GAGG * 128 * 4);
    float* partials2 = (float*)alloc((size_t)256 * 128 * 4);
    int2* meta_e     = (int2*)alloc((size_t)NBUCK * B_KEYS * 8);
    int2* meta_n     = (int2*)alloc((size_t)NBUCK * B_KEYS * 8);
    short* WT1       = (short*)alloc((size_t)128 * 128 * 2);
    short* WT2       = (short*)alloc((size_t)128 * 128 * 2);
    int* gcnt        = (int*)alloc((size_t)2 * NBUCK * 4);
    int* gcnt_e = gcnt;
    int* gcnt_n = gcnt + NBUCK;

    wt_kernel<<<128, 256, 0, stream>>>(w1, w2, WT1, WT2, gcnt);
    binA_kernel<<<NBLKA, 256, 0, stream>>>(nidx, hidx, gcnt_e, gcnt_n, bin_e, bin_n);
    binB2_kernel<<<2 * NBUCK, 512, 0, stream>>>(gcnt_e, bin_e, csr_e, meta_e,
                                                gcnt_n, bin_n, csr_n, meta_n);

    int gGemm = (N_NODES + 63) / 64;

    // layer 1
    gemm_mfma_kernel<float><<<gGemm, 256, 0, stream>>>(x, WT1, A, N_NODES);
    agg_fp8_kernel<0><<<GAGG, 256, 0, stream>>>(A, meta_e, csr_e, nullptr, E);
    agg_fp8_kernel<1><<<GAGG, 256, 0, stream>>>(E, meta_n, csr_n, b1, O);
    // layer 2
    gemm_mfma_kernel<__hip_bfloat16><<<gGemm, 256, 0, stream>>>((const __hip_bfloat16*)O, WT2, A, N_NODES);
    agg_fp8_kernel<0><<<GAGG, 256, 0, stream>>>(A, meta_e, csr_e, nullptr, E);
    agg_fp8_kernel<2><<<GAGG, 256, 0, stream>>>(E, meta_n, csr_n, b2, partials);
    mean_stage1_kernel<<<256, 256, 0, stream>>>(partials, partials2, GAGG);
    mean_stage2_kernel<<<1, 256, 0, stream>>>(partials2, out);
}